// Round 6
// baseline (664.128 us; speedup 1.0000x reference)
//
#include <hip/hip_runtime.h>
#include <hip/hip_bf16.h>

#define NN 50000
#define NE 800000
#define NG 512

typedef __bf16 bf16_t;
typedef __bf16 bf16x8 __attribute__((ext_vector_type(8)));
typedef __bf16 bf16x4 __attribute__((ext_vector_type(4)));
typedef float f32x4 __attribute__((ext_vector_type(4)));
typedef float f32x2 __attribute__((ext_vector_type(2)));

__device__ __forceinline__ float lrelu(float v) { return v >= 0.f ? v : 0.01f * v; }

// unpack 2 bf16 (packed in one u32) -> float2 (pair order: lo, hi)
__device__ __forceinline__ f32x2 unpk2(unsigned w) {
    union { unsigned u; float f; } lo, hi;
    lo.u = w << 16;
    hi.u = w & 0xffff0000u;
    f32x2 r; r[0] = lo.f; r[1] = hi.f; return r;
}

// ---------------- tiny precomputes ----------------
__global__ void gme_setup(const float* __restrict__ emb,
                          const float* __restrict__ c1lw, const float* __restrict__ c1l2w,
                          const float* __restrict__ c1l2b, const float* __restrict__ c1lb,
                          const float* __restrict__ c2lw, const float* __restrict__ c2l2w,
                          const float* __restrict__ c2l2b, const float* __restrict__ c2lb,
                          float* __restrict__ TY, float* __restrict__ WC1, float* __restrict__ CB1,
                          float* __restrict__ WC2, float* __restrict__ CB2,
                          bf16_t* __restrict__ W2B) {
    int b = blockIdx.x, t = threadIdx.x;
    if (b < 51) {
        const float* er = emb + b * 128;
        const float* wr = c1lw + t * 128;
        float s = 0.f;
        for (int k = 0; k < 128; ++k) s += er[k] * wr[k];
        TY[b * 256 + t] = s;
    } else if (b == 51) {
        const float* wr = c1lw + t * 128;
        float a0 = 0, a1 = 0, a2 = 0, a3 = 0, ab = 0;
        for (int k = 0; k < 128; ++k) {
            float w = wr[k];
            a0 += w * c1l2w[k * 4 + 0]; a1 += w * c1l2w[k * 4 + 1];
            a2 += w * c1l2w[k * 4 + 2]; a3 += w * c1l2w[k * 4 + 3];
            ab += w * c1l2b[k];
        }
        WC1[t * 4 + 0] = a0; WC1[t * 4 + 1] = a1; WC1[t * 4 + 2] = a2; WC1[t * 4 + 3] = a3;
        CB1[t] = ab + c1lb[t];
    } else if (b == 52) {
        const float* wr = c2lw + t * 256;
        float a0 = 0, a1 = 0, a2 = 0, a3 = 0, ab = 0;
        for (int k = 0; k < 256; ++k) {
            float w = wr[k];
            a0 += w * c2l2w[k * 4 + 0]; a1 += w * c2l2w[k * 4 + 1];
            a2 += w * c2l2w[k * 4 + 2]; a3 += w * c2l2w[k * 4 + 3];
            ab += w * c2l2b[k];
        }
        WC2[t * 4 + 0] = a0; WC2[t * 4 + 1] = a1; WC2[t * 4 + 2] = a2; WC2[t * 4 + 3] = a3;
        CB2[t] = ab + c2lb[t];
    } else {
        int i0 = (b - 53) * 1024;
        for (int r = 0; r < 4; ++r) {
            int i = i0 + r * 256 + t;
            W2B[i] = (bf16_t)c2lw[i];
        }
    }
}

// ---------------- CSR build ----------------
__global__ void gme_count(const int* __restrict__ ei, int* __restrict__ cnt) {
    int e = blockIdx.x * 256 + threadIdx.x;
    if (e >= NE) return;
    atomicAdd(&cnt[ei[NE + e]], 1);
}

__global__ void gme_scan1(const int* __restrict__ CNT, int* __restrict__ LP,
                          int* __restrict__ BS) {
    __shared__ int lds[256];
    int b = blockIdx.x, t = threadIdx.x;
    int i = b * 196 + t;
    int v = (t < 196 && i < NN) ? CNT[i] : 0;
    lds[t] = v;
    __syncthreads();
    for (int off = 1; off < 256; off <<= 1) {
        int u = (t >= off) ? lds[t - off] : 0;
        __syncthreads();
        lds[t] += u;
        __syncthreads();
    }
    if (t < 196 && i < NN) LP[i] = lds[t] - v;
    if (t == 255) BS[b] = lds[255];
}

__global__ void gme_scan2(const int* __restrict__ BS, int* __restrict__ BX,
                          int* __restrict__ RS) {
    __shared__ int lds[256];
    int t = threadIdx.x;
    int v = BS[t];
    lds[t] = v;
    __syncthreads();
    for (int off = 1; off < 256; off <<= 1) {
        int u = (t >= off) ? lds[t - off] : 0;
        __syncthreads();
        lds[t] += u;
        __syncthreads();
    }
    BX[t] = lds[t] - v;
    if (t == 255) RS[NN] = lds[255];
}

__global__ void gme_scan3(const int* __restrict__ LP, const int* __restrict__ BX,
                          int* __restrict__ RS, int* __restrict__ CUR) {
    int b = blockIdx.x, t = threadIdx.x;
    if (t >= 196) return;
    int i = b * 196 + t;
    if (i >= NN) return;
    int v = BX[b] + LP[i];
    RS[i] = v;
    CUR[i] = v;
}

__global__ void gme_scatter(const int* __restrict__ ei, const float4* __restrict__ eattr,
                            const int* __restrict__ node_ids,
                            int* __restrict__ CUR, int* __restrict__ S0,
                            int* __restrict__ S1, float4* __restrict__ Sattr) {
    int e = blockIdx.x * 256 + threadIdx.x;
    if (e >= NE) return;
    int s = ei[e];
    int d = ei[NE + e];
    int pos = atomicAdd(&CUR[d], 1);
    S0[pos] = s;
    S1[pos] = node_ids[s];
    Sattr[pos] = eattr[e];
}

// ---------------- edge aggregation (packed-f32 math) ----------------
// one wave per node, lane = 4 channels as two float2 pairs; 4-edge unroll.
template <int BF>
__global__ __launch_bounds__(256) void gme_conv(
        const int* __restrict__ RS, const int* __restrict__ Src,
        const float4* __restrict__ Sattr, const float* __restrict__ ybf32,
        const bf16_t* __restrict__ ybf16,
        const float* __restrict__ Wc, const float* __restrict__ cb,
        float* __restrict__ agg) {
    int lane = threadIdx.x & 63;
    int node = blockIdx.x * 4 + (threadIdx.x >> 6);
    if (node >= NN) return;
    const float4* wc4 = (const float4*)Wc;
    int c4 = lane * 4;
    float4 w0 = wc4[c4 + 0], w1 = wc4[c4 + 1], w2 = wc4[c4 + 2], w3 = wc4[c4 + 3];
    float4 bz4 = ((const float4*)cb)[lane];
    // pair repack: pair0 = (ch0,ch1), pair1 = (ch2,ch3); wXk = attr-comp k weights
    f32x2 wA0 = {w0.x, w1.x}, wB0 = {w0.y, w1.y}, wC0 = {w0.z, w1.z}, wD0 = {w0.w, w1.w};
    f32x2 wA1 = {w2.x, w3.x}, wB1 = {w2.y, w3.y}, wC1 = {w2.z, w3.z}, wD1 = {w2.w, w3.w};
    f32x2 bz0 = {bz4.x, bz4.y}, bz1 = {bz4.z, bz4.w};
    const f32x2 zero = {0.f, 0.f};
    const f32x2 slope = {0.01f, 0.01f};
    f32x2 acc0 = zero, acc1 = zero;
    int rs = RS[node], re = RS[node + 1];

    struct Row { f32x2 y0, y1; };
    auto rowld = [&](int row) -> Row {
        Row r;
        if (BF) {
            uint2 u = *((const uint2*)(ybf16 + row * 256) + lane);
            r.y0 = unpk2(u.x);
            r.y1 = unpk2(u.y);
        } else {
            float4 y = *((const float4*)(ybf32 + row * 256) + lane);
            r.y0[0] = y.x; r.y0[1] = y.y;
            r.y1[0] = y.z; r.y1[1] = y.w;
        }
        return r;
    };
    auto accum = [&](float4 a, Row r) {
        f32x2 ax = {a.x, a.x}, ay = {a.y, a.y}, az = {a.z, a.z}, aw = {a.w, a.w};
        f32x2 m0 = __builtin_elementwise_fma(ax, wA0, bz0);
        f32x2 m1 = __builtin_elementwise_fma(ax, wA1, bz1);
        m0 = __builtin_elementwise_fma(ay, wB0, m0);
        m1 = __builtin_elementwise_fma(ay, wB1, m1);
        m0 = __builtin_elementwise_fma(az, wC0, m0);
        m1 = __builtin_elementwise_fma(az, wC1, m1);
        m0 = __builtin_elementwise_fma(aw, wD0, m0);
        m1 = __builtin_elementwise_fma(aw, wD1, m1);
        m0 += r.y0;
        m1 += r.y1;
        // lrelu: max(m,0) + 0.01*min(m,0), packed
        acc0 += __builtin_elementwise_max(m0, zero);
        acc1 += __builtin_elementwise_max(m1, zero);
        acc0 = __builtin_elementwise_fma(__builtin_elementwise_min(m0, zero), slope, acc0);
        acc1 = __builtin_elementwise_fma(__builtin_elementwise_min(m1, zero), slope, acc1);
    };

    int j = rs;
    for (; j + 4 <= re; j += 4) {
        int s0 = Src[j], s1 = Src[j + 1], s2 = Src[j + 2], s3 = Src[j + 3];
        float4 a0 = Sattr[j], a1 = Sattr[j + 1], a2 = Sattr[j + 2], a3 = Sattr[j + 3];
        Row r0 = rowld(s0);
        Row r1 = rowld(s1);
        Row r2 = rowld(s2);
        Row r3 = rowld(s3);
        accum(a0, r0); accum(a1, r1); accum(a2, r2); accum(a3, r3);
    }
    for (; j < re; ++j) {
        float4 a = Sattr[j];
        accum(a, rowld(Src[j]));
    }
    *((float4*)(agg + node * 256) + lane) = make_float4(acc0[0], acc0[1], acc1[0], acc1[1]);
}

// ---------------- BN stats: wave-per-node float4, LDS block reduce ----------------
__global__ __launch_bounds__(256) void gme_bnstats(const float* __restrict__ P,
                                                   float* __restrict__ ST) {
    __shared__ float ls[4][256], lq[4][256];
    int lane = threadIdx.x & 63;
    int w = threadIdx.x >> 6;
    int gw = blockIdx.x * 4 + w;
    int tot = gridDim.x * 4;
    float4 s = make_float4(0, 0, 0, 0), q = make_float4(0, 0, 0, 0);
    for (int n = gw; n < NN; n += tot) {
        float4 v = ((const float4*)P)[n * 64 + lane];
        s.x += v.x; s.y += v.y; s.z += v.z; s.w += v.w;
        q.x += v.x * v.x; q.y += v.y * v.y; q.z += v.z * v.z; q.w += v.w * v.w;
    }
    int c = lane * 4;
    ls[w][c] = s.x; ls[w][c + 1] = s.y; ls[w][c + 2] = s.z; ls[w][c + 3] = s.w;
    lq[w][c] = q.x; lq[w][c + 1] = q.y; lq[w][c + 2] = q.z; lq[w][c + 3] = q.w;
    __syncthreads();
    if (w == 0) {
        for (int k = 0; k < 4; ++k) {
            int cc = c + k;
            float ssum = ls[0][cc] + ls[1][cc] + ls[2][cc] + ls[3][cc];
            float qsum = lq[0][cc] + lq[1][cc] + lq[2][cc] + lq[3][cc];
            atomicAdd(&ST[cc], ssum);
            atomicAdd(&ST[256 + cc], qsum);
        }
    }
}

// ---------------- GEMM with fused BN1+LeakyReLU on the A operand ----------------
__global__ __launch_bounds__(256) void gme_gemm(const float* __restrict__ P,
                                                const float* __restrict__ ST,
                                                const float* __restrict__ bw,
                                                const float* __restrict__ bb,
                                                const bf16_t* __restrict__ W2B,
                                                bf16_t* __restrict__ QB) {
    __shared__ float s_sc[256], s_sh[256];
    {
        int c = threadIdx.x;
        float mean = ST[c] * (1.f / NN);
        float var = ST[256 + c] * (1.f / NN) - mean * mean;
        float sc = bw[c] * rsqrtf(var + 1e-5f);
        s_sc[c] = sc;
        s_sh[c] = bb[c] - mean * sc;
    }
    __syncthreads();
    int lane = threadIdx.x & 63;
    int wave = blockIdx.x * 4 + (threadIdx.x >> 6);
    if (wave >= NN / 16) return;
    int m0 = wave * 16;
    int r = lane & 15, q = lane >> 4;
    const float* arow = P + (m0 + r) * 256 + q * 8;
    bf16x8 a[8];
#pragma unroll
    for (int kt = 0; kt < 8; ++kt) {
        int k0 = kt * 32 + q * 8;
        float4 u0 = *(const float4*)(arow + kt * 32);
        float4 u1 = *(const float4*)(arow + kt * 32 + 4);
        bf16x8 f;
        f[0] = (bf16_t)lrelu(fmaf(u0.x, s_sc[k0 + 0], s_sh[k0 + 0]));
        f[1] = (bf16_t)lrelu(fmaf(u0.y, s_sc[k0 + 1], s_sh[k0 + 1]));
        f[2] = (bf16_t)lrelu(fmaf(u0.z, s_sc[k0 + 2], s_sh[k0 + 2]));
        f[3] = (bf16_t)lrelu(fmaf(u0.w, s_sc[k0 + 3], s_sh[k0 + 3]));
        f[4] = (bf16_t)lrelu(fmaf(u1.x, s_sc[k0 + 4], s_sh[k0 + 4]));
        f[5] = (bf16_t)lrelu(fmaf(u1.y, s_sc[k0 + 5], s_sh[k0 + 5]));
        f[6] = (bf16_t)lrelu(fmaf(u1.z, s_sc[k0 + 6], s_sh[k0 + 6]));
        f[7] = (bf16_t)lrelu(fmaf(u1.w, s_sc[k0 + 7], s_sh[k0 + 7]));
        a[kt] = f;
    }
#pragma unroll
    for (int nt = 0; nt < 16; ++nt) {
        f32x4 acc = {0.f, 0.f, 0.f, 0.f};
        const bf16_t* brow = W2B + (nt * 16 + r) * 256 + q * 8;
#pragma unroll
        for (int kt = 0; kt < 8; ++kt) {
            bf16x8 bfrag = *(const bf16x8*)(brow + kt * 32);
            acc = __builtin_amdgcn_mfma_f32_16x16x32_bf16(a[kt], bfrag, acc, 0, 0, 0);
        }
        bf16_t* yo = QB + (m0 + q * 4) * 256 + nt * 16 + r;
        yo[0] = (bf16_t)acc[0]; yo[256] = (bf16_t)acc[1];
        yo[512] = (bf16_t)acc[2]; yo[768] = (bf16_t)acc[3];
    }
}

// ---------------- gate only (BN2 applied on the fly, P left raw) ----------------
__global__ __launch_bounds__(256) void gme_x2g(const float* __restrict__ P,
                                               const float* __restrict__ ST,
                                               const float* __restrict__ bw,
                                               const float* __restrict__ bb,
                                               const float* __restrict__ gw,
                                               const float* __restrict__ gb,
                                               float* __restrict__ GATE) {
    int lane = threadIdx.x & 63;
    int node = blockIdx.x * 4 + (threadIdx.x >> 6);
    if (node >= NN) return;
    float4 s = ((const float4*)ST)[lane];
    float4 qq = ((const float4*)(ST + 256))[lane];
    float4 w = ((const float4*)bw)[lane];
    float4 b = ((const float4*)bb)[lane];
    float4 g = ((const float4*)gw)[lane];
    float m0 = s.x * (1.f / NN), m1 = s.y * (1.f / NN), m2 = s.z * (1.f / NN), m3 = s.w * (1.f / NN);
    float sc0 = w.x * rsqrtf(qq.x * (1.f / NN) - m0 * m0 + 1e-5f);
    float sc1 = w.y * rsqrtf(qq.y * (1.f / NN) - m1 * m1 + 1e-5f);
    float sc2 = w.z * rsqrtf(qq.z * (1.f / NN) - m2 * m2 + 1e-5f);
    float sc3 = w.w * rsqrtf(qq.w * (1.f / NN) - m3 * m3 + 1e-5f);
    float sh0 = b.x - m0 * sc0, sh1 = b.y - m1 * sc1, sh2 = b.z - m2 * sc2, sh3 = b.w - m3 * sc3;
    float4 p = ((const float4*)P)[node * 64 + lane];
    float v0 = lrelu(fmaf(p.x, sc0, sh0));
    float v1 = lrelu(fmaf(p.y, sc1, sh1));
    float v2 = lrelu(fmaf(p.z, sc2, sh2));
    float v3 = lrelu(fmaf(p.w, sc3, sh3));
    float dot = v0 * g.x + v1 * g.y + v2 * g.z + v3 * g.w;
#pragma unroll
    for (int off = 32; off > 0; off >>= 1) dot += __shfl_xor(dot, off, 64);
    if (lane == 0) GATE[node] = dot + gb[0];
}

// ---------------- graph segment boundaries ----------------
__global__ void gme_gstart(const int* __restrict__ batch, int* __restrict__ GS) {
    int n = blockIdx.x * 256 + threadIdx.x;
    if (n >= NN) return;
    int b = batch[n];
    if (n == 0) {
        for (int g = 0; g <= b; ++g) GS[g] = 0;
    } else {
        int a = batch[n - 1];
        for (int g = a + 1; g <= b; ++g) GS[g] = n;
    }
    if (n == NN - 1) {
        for (int g = b + 1; g <= NG; ++g) GS[g] = NN;
    }
}

// ---------------- attentional aggregation, BN2+lrelu inline (f32 output) ------
__global__ void gme_attn(const int* __restrict__ GS, const float* __restrict__ GATE,
                         const float* __restrict__ P, const float* __restrict__ ST,
                         const float* __restrict__ bw, const float* __restrict__ bb,
                         float* __restrict__ out) {
    __shared__ float red[256];
    int g = blockIdx.x, t = threadIdx.x;
    int lo = GS[g], hi = GS[g + 1];
    if (lo >= hi) { out[g * 256 + t] = 0.f; return; }
    float mean = ST[t] * (1.f / NN);
    float var = ST[256 + t] * (1.f / NN) - mean * mean;
    float sc = bw[t] * rsqrtf(var + 1e-5f);
    float sh = bb[t] - mean * sc;
    float lm = -3.0e38f;
    for (int n = lo + t; n < hi; n += 256) lm = fmaxf(lm, GATE[n]);
    red[t] = lm; __syncthreads();
    for (int s = 128; s > 0; s >>= 1) { if (t < s) red[t] = fmaxf(red[t], red[t + s]); __syncthreads(); }
    float m = red[0]; __syncthreads();
    float ls = 0.f;
    for (int n = lo + t; n < hi; n += 256) ls += expf(GATE[n] - m);
    red[t] = ls; __syncthreads();
    for (int s = 128; s > 0; s >>= 1) { if (t < s) red[t] += red[t + s]; __syncthreads(); }
    float sinv = 1.f / red[0];
    float acc = 0.f;
    int n = lo;
    for (; n + 2 <= hi; n += 2) {
        float w0 = expf(GATE[n] - m), w1 = expf(GATE[n + 1] - m);
        float p0 = P[n * 256 + t], p1 = P[(n + 1) * 256 + t];
        acc = fmaf(w0, lrelu(fmaf(p0, sc, sh)), acc);
        acc = fmaf(w1, lrelu(fmaf(p1, sc, sh)), acc);
    }
    if (n < hi) {
        float w0 = expf(GATE[n] - m);
        acc = fmaf(w0, lrelu(fmaf(P[n * 256 + t], sc, sh)), acc);
    }
    out[g * 256 + t] = acc * sinv;
}

extern "C" void kernel_launch(void* const* d_in, const int* in_sizes, int n_in,
                              void* d_out, int out_size, void* d_ws, size_t ws_size,
                              hipStream_t stream) {
    const int* node_ids = (const int*)d_in[0];
    const int* edge_index = (const int*)d_in[1];
    const float4* edge_attr = (const float4*)d_in[2];
    const int* batch = (const int*)d_in[3];
    const float* emb = (const float*)d_in[4];
    const float* c1l2w = (const float*)d_in[5];
    const float* c1l2b = (const float*)d_in[6];
    const float* c1lw = (const float*)d_in[7];
    const float* c1lb = (const float*)d_in[8];
    const float* bn1w = (const float*)d_in[9];
    const float* bn1b = (const float*)d_in[10];
    const float* c2l2w = (const float*)d_in[11];
    const float* c2l2b = (const float*)d_in[12];
    const float* c2lw = (const float*)d_in[13];
    const float* c2lb = (const float*)d_in[14];
    const float* bn2w = (const float*)d_in[15];
    const float* bn2b = (const float*)d_in[16];
    const float* gate_w = (const float*)d_in[17];
    const float* gate_b = (const float*)d_in[18];

    char* ws = (char*)d_ws;
    size_t oP = 0;                        // f32 [50000,256]
    size_t oQB = oP + 51200000;           // bf16 [50000,256]
    size_t oS0 = oQB + 25600000;          // int [800000] src
    size_t oS1 = oS0 + 3200000;           // int [800000] node_ids[src]
    size_t oSattr = oS1 + 3200000;        // float4 [800000]
    size_t oRS = oSattr + 12800000;       // int [50001]
    size_t oCNT = oRS + 200064;           // int [50000]
    size_t oCUR = oCNT + 200000;          // int [50000]
    size_t oLP = oCUR + 200000;           // int [50000]
    size_t oBS = oLP + 200000;            // int [256]
    size_t oBX = oBS + 1024;              // int [256]
    size_t oTY = oBX + 1024;              // f32 [51,256]
    size_t oWC1 = oTY + 52224;            // f32 [256,4]
    size_t oCB1 = oWC1 + 4096;            // f32 [256]
    size_t oWC2 = oCB1 + 1024;            // f32 [256,4]
    size_t oCB2 = oWC2 + 4096;            // f32 [256]
    size_t oW2B = oCB2 + 1024;            // bf16 [256,256]
    size_t oST = oW2B + 131072;           // f32 [1024]: ST1+ST2
    size_t oGATE = oST + 4096;            // f32 [50000]
    size_t oGS = oGATE + 200000;          // int [513]

    float* P = (float*)(ws + oP);
    bf16_t* QB = (bf16_t*)(ws + oQB);
    int* S0 = (int*)(ws + oS0);
    int* S1 = (int*)(ws + oS1);
    float4* Sattr = (float4*)(ws + oSattr);
    int* RS = (int*)(ws + oRS);
    int* CNT = (int*)(ws + oCNT);
    int* CUR = (int*)(ws + oCUR);
    int* LP = (int*)(ws + oLP);
    int* BS = (int*)(ws + oBS);
    int* BX = (int*)(ws + oBX);
    float* TY = (float*)(ws + oTY);
    float* WC1 = (float*)(ws + oWC1);
    float* CB1 = (float*)(ws + oCB1);
    float* WC2 = (float*)(ws + oWC2);
    float* CB2 = (float*)(ws + oCB2);
    bf16_t* W2B = (bf16_t*)(ws + oW2B);
    float* ST1 = (float*)(ws + oST);
    float* ST2 = ST1 + 512;
    float* GATE = (float*)(ws + oGATE);
    int* GS = (int*)(ws + oGS);

    hipMemsetAsync(CNT, 0, NN * sizeof(int), stream);
    hipMemsetAsync(ST1, 0, 1024 * sizeof(float), stream);

    gme_setup<<<117, 256, 0, stream>>>(emb, c1lw, c1l2w, c1l2b, c1lb,
                                       c2lw, c2l2w, c2l2b, c2lb,
                                       TY, WC1, CB1, WC2, CB2, W2B);
    gme_count<<<NE / 256, 256, 0, stream>>>(edge_index, CNT);
    gme_scan1<<<256, 256, 0, stream>>>(CNT, LP, BS);
    gme_scan2<<<1, 256, 0, stream>>>(BS, BX, RS);
    gme_scan3<<<256, 256, 0, stream>>>(LP, BX, RS, CUR);
    gme_scatter<<<NE / 256, 256, 0, stream>>>(edge_index, edge_attr, node_ids,
                                              CUR, S0, S1, Sattr);
    gme_gstart<<<(NN + 255) / 256, 256, 0, stream>>>(batch, GS);
    // conv1: rows from 51x256 f32 table via pre-mapped S1
    gme_conv<0><<<NN / 4, 256, 0, stream>>>(RS, S1, Sattr, TY, nullptr, WC1, CB1, P);
    gme_bnstats<<<1024, 256, 0, stream>>>(P, ST1);
    gme_gemm<<<(NN / 16 + 3) / 4, 256, 0, stream>>>(P, ST1, bn1w, bn1b, W2B, QB);
    // conv2: rows from bf16 y2 table via S0
    gme_conv<1><<<NN / 4, 256, 0, stream>>>(RS, S0, Sattr, nullptr, QB, WC2, CB2, P);
    gme_bnstats<<<1024, 256, 0, stream>>>(P, ST2);
    gme_x2g<<<NN / 4, 256, 0, stream>>>(P, ST2, bn2w, bn2b, gate_w, gate_b, GATE);
    gme_attn<<<NG, 256, 0, stream>>>(GS, GATE, P, ST2, bn2w, bn2b, (float*)d_out);
}

// Round 7
// 521.334 us; speedup vs baseline: 1.2739x; 1.2739x over previous
//
#include <hip/hip_runtime.h>
#include <hip/hip_bf16.h>

#define NN 50000
#define NE 800000
#define NG 512

typedef __bf16 bf16_t;
typedef __bf16 bf16x8 __attribute__((ext_vector_type(8)));
typedef __bf16 bf16x4 __attribute__((ext_vector_type(4)));
typedef float f32x4 __attribute__((ext_vector_type(4)));
typedef float f32x2 __attribute__((ext_vector_type(2)));

__device__ __forceinline__ float lrelu(float v) { return v >= 0.f ? v : 0.01f * v; }

// unpack 2 bf16 (packed in one u32) -> float2 (pair order: lo, hi)
__device__ __forceinline__ f32x2 unpk2(unsigned w) {
    union { unsigned u; float f; } lo, hi;
    lo.u = w << 16;
    hi.u = w & 0xffff0000u;
    f32x2 r; r[0] = lo.f; r[1] = hi.f; return r;
}

// ---------------- tiny precomputes ----------------
__global__ void gme_setup(const float* __restrict__ emb,
                          const float* __restrict__ c1lw, const float* __restrict__ c1l2w,
                          const float* __restrict__ c1l2b, const float* __restrict__ c1lb,
                          const float* __restrict__ c2lw, const float* __restrict__ c2l2w,
                          const float* __restrict__ c2l2b, const float* __restrict__ c2lb,
                          float* __restrict__ TY, float* __restrict__ WC1, float* __restrict__ CB1,
                          float* __restrict__ WC2, float* __restrict__ CB2,
                          bf16_t* __restrict__ W2B) {
    int b = blockIdx.x, t = threadIdx.x;
    if (b < 51) {
        const float* er = emb + b * 128;
        const float* wr = c1lw + t * 128;
        float s = 0.f;
        for (int k = 0; k < 128; ++k) s += er[k] * wr[k];
        TY[b * 256 + t] = s;
    } else if (b == 51) {
        const float* wr = c1lw + t * 128;
        float a0 = 0, a1 = 0, a2 = 0, a3 = 0, ab = 0;
        for (int k = 0; k < 128; ++k) {
            float w = wr[k];
            a0 += w * c1l2w[k * 4 + 0]; a1 += w * c1l2w[k * 4 + 1];
            a2 += w * c1l2w[k * 4 + 2]; a3 += w * c1l2w[k * 4 + 3];
            ab += w * c1l2b[k];
        }
        WC1[t * 4 + 0] = a0; WC1[t * 4 + 1] = a1; WC1[t * 4 + 2] = a2; WC1[t * 4 + 3] = a3;
        CB1[t] = ab + c1lb[t];
    } else if (b == 52) {
        const float* wr = c2lw + t * 256;
        float a0 = 0, a1 = 0, a2 = 0, a3 = 0, ab = 0;
        for (int k = 0; k < 256; ++k) {
            float w = wr[k];
            a0 += w * c2l2w[k * 4 + 0]; a1 += w * c2l2w[k * 4 + 1];
            a2 += w * c2l2w[k * 4 + 2]; a3 += w * c2l2w[k * 4 + 3];
            ab += w * c2l2b[k];
        }
        WC2[t * 4 + 0] = a0; WC2[t * 4 + 1] = a1; WC2[t * 4 + 2] = a2; WC2[t * 4 + 3] = a3;
        CB2[t] = ab + c2lb[t];
    } else {
        int i0 = (b - 53) * 1024;
        for (int r = 0; r < 4; ++r) {
            int i = i0 + r * 256 + t;
            W2B[i] = (bf16_t)c2lw[i];
        }
    }
}

// ---------------- CSR build ----------------
__global__ void gme_count(const int* __restrict__ ei, int* __restrict__ cnt) {
    int e = blockIdx.x * 256 + threadIdx.x;
    if (e >= NE) return;
    atomicAdd(&cnt[ei[NE + e]], 1);
}

__global__ void gme_scan1(const int* __restrict__ CNT, int* __restrict__ LP,
                          int* __restrict__ BS) {
    __shared__ int lds[256];
    int b = blockIdx.x, t = threadIdx.x;
    int i = b * 196 + t;
    int v = (t < 196 && i < NN) ? CNT[i] : 0;
    lds[t] = v;
    __syncthreads();
    for (int off = 1; off < 256; off <<= 1) {
        int u = (t >= off) ? lds[t - off] : 0;
        __syncthreads();
        lds[t] += u;
        __syncthreads();
    }
    if (t < 196 && i < NN) LP[i] = lds[t] - v;
    if (t == 255) BS[b] = lds[255];
}

__global__ void gme_scan2(const int* __restrict__ BS, int* __restrict__ BX,
                          int* __restrict__ RS) {
    __shared__ int lds[256];
    int t = threadIdx.x;
    int v = BS[t];
    lds[t] = v;
    __syncthreads();
    for (int off = 1; off < 256; off <<= 1) {
        int u = (t >= off) ? lds[t - off] : 0;
        __syncthreads();
        lds[t] += u;
        __syncthreads();
    }
    BX[t] = lds[t] - v;
    if (t == 255) RS[NN] = lds[255];
}

__global__ void gme_scan3(const int* __restrict__ LP, const int* __restrict__ BX,
                          int* __restrict__ RS, int* __restrict__ CUR) {
    int b = blockIdx.x, t = threadIdx.x;
    if (t >= 196) return;
    int i = b * 196 + t;
    if (i >= NN) return;
    int v = BX[b] + LP[i];
    RS[i] = v;
    CUR[i] = v;
}

__global__ void gme_scatter(const int* __restrict__ ei, const float4* __restrict__ eattr,
                            const int* __restrict__ node_ids,
                            int* __restrict__ CUR, int* __restrict__ S0,
                            int* __restrict__ S1, float4* __restrict__ Sattr) {
    int e = blockIdx.x * 256 + threadIdx.x;
    if (e >= NE) return;
    int s = ei[e];
    int d = ei[NE + e];
    int pos = atomicAdd(&CUR[d], 1);
    S0[pos] = s;
    S1[pos] = node_ids[s];
    Sattr[pos] = eattr[e];
}

// ---------------- edge aggregation (packed-f32 math) ----------------
template <int BF>
__global__ __launch_bounds__(256) void gme_conv(
        const int* __restrict__ RS, const int* __restrict__ Src,
        const float4* __restrict__ Sattr, const float* __restrict__ ybf32,
        const bf16_t* __restrict__ ybf16,
        const float* __restrict__ Wc, const float* __restrict__ cb,
        float* __restrict__ agg) {
    int lane = threadIdx.x & 63;
    int node = blockIdx.x * 4 + (threadIdx.x >> 6);
    if (node >= NN) return;
    const float4* wc4 = (const float4*)Wc;
    int c4 = lane * 4;
    float4 w0 = wc4[c4 + 0], w1 = wc4[c4 + 1], w2 = wc4[c4 + 2], w3 = wc4[c4 + 3];
    float4 bz4 = ((const float4*)cb)[lane];
    f32x2 wA0 = {w0.x, w1.x}, wB0 = {w0.y, w1.y}, wC0 = {w0.z, w1.z}, wD0 = {w0.w, w1.w};
    f32x2 wA1 = {w2.x, w3.x}, wB1 = {w2.y, w3.y}, wC1 = {w2.z, w3.z}, wD1 = {w2.w, w3.w};
    f32x2 bz0 = {bz4.x, bz4.y}, bz1 = {bz4.z, bz4.w};
    const f32x2 zero = {0.f, 0.f};
    const f32x2 slope = {0.01f, 0.01f};
    f32x2 acc0 = zero, acc1 = zero;
    int rs = RS[node], re = RS[node + 1];

    struct Row { f32x2 y0, y1; };
    auto rowld = [&](int row) -> Row {
        Row r;
        if (BF) {
            uint2 u = *((const uint2*)(ybf16 + row * 256) + lane);
            r.y0 = unpk2(u.x);
            r.y1 = unpk2(u.y);
        } else {
            float4 y = *((const float4*)(ybf32 + row * 256) + lane);
            r.y0[0] = y.x; r.y0[1] = y.y;
            r.y1[0] = y.z; r.y1[1] = y.w;
        }
        return r;
    };
    auto accum = [&](float4 a, Row r) {
        f32x2 ax = {a.x, a.x}, ay = {a.y, a.y}, az = {a.z, a.z}, aw = {a.w, a.w};
        f32x2 m0 = __builtin_elementwise_fma(ax, wA0, bz0);
        f32x2 m1 = __builtin_elementwise_fma(ax, wA1, bz1);
        m0 = __builtin_elementwise_fma(ay, wB0, m0);
        m1 = __builtin_elementwise_fma(ay, wB1, m1);
        m0 = __builtin_elementwise_fma(az, wC0, m0);
        m1 = __builtin_elementwise_fma(az, wC1, m1);
        m0 = __builtin_elementwise_fma(aw, wD0, m0);
        m1 = __builtin_elementwise_fma(aw, wD1, m1);
        m0 += r.y0;
        m1 += r.y1;
        acc0 += __builtin_elementwise_max(m0, zero);
        acc1 += __builtin_elementwise_max(m1, zero);
        acc0 = __builtin_elementwise_fma(__builtin_elementwise_min(m0, zero), slope, acc0);
        acc1 = __builtin_elementwise_fma(__builtin_elementwise_min(m1, zero), slope, acc1);
    };

    int j = rs;
    for (; j + 4 <= re; j += 4) {
        int s0 = Src[j], s1 = Src[j + 1], s2 = Src[j + 2], s3 = Src[j + 3];
        float4 a0 = Sattr[j], a1 = Sattr[j + 1], a2 = Sattr[j + 2], a3 = Sattr[j + 3];
        Row r0 = rowld(s0);
        Row r1 = rowld(s1);
        Row r2 = rowld(s2);
        Row r3 = rowld(s3);
        accum(a0, r0); accum(a1, r1); accum(a2, r2); accum(a3, r3);
    }
    for (; j < re; ++j) {
        float4 a = Sattr[j];
        accum(a, rowld(Src[j]));
    }
    *((float4*)(agg + node * 256) + lane) = make_float4(acc0[0], acc0[1], acc1[0], acc1[1]);
}

// ---------------- BN stats: two-stage, atomic-free ----------------
// stage 1: 512 blocks x (4 waves); block b covers rows [b*98, b*98+98);
// lane=4 channels float4; LDS cross-wave reduce; one plain 512-float store.
__global__ __launch_bounds__(256) void gme_bns1(const float* __restrict__ P,
                                                float* __restrict__ PART) {
    __shared__ float ls[4][256], lq[4][256];
    int lane = threadIdx.x & 63;
    int w = threadIdx.x >> 6;
    int b = blockIdx.x;
    int r0 = b * 98;
    int r1 = r0 + 98; if (r1 > NN) r1 = NN;
    float4 s = make_float4(0, 0, 0, 0), q = make_float4(0, 0, 0, 0);
    for (int n = r0 + w; n < r1; n += 4) {
        float4 v = ((const float4*)P)[n * 64 + lane];
        s.x += v.x; s.y += v.y; s.z += v.z; s.w += v.w;
        q.x += v.x * v.x; q.y += v.y * v.y; q.z += v.z * v.z; q.w += v.w * v.w;
    }
    int c = lane * 4;
    ls[w][c] = s.x; ls[w][c + 1] = s.y; ls[w][c + 2] = s.z; ls[w][c + 3] = s.w;
    lq[w][c] = q.x; lq[w][c + 1] = q.y; lq[w][c + 2] = q.z; lq[w][c + 3] = q.w;
    __syncthreads();
    if (w == 0) {
#pragma unroll
        for (int k = 0; k < 4; ++k) {
            int cc = c + k;
            PART[b * 512 + cc] = ls[0][cc] + ls[1][cc] + ls[2][cc] + ls[3][cc];
            PART[b * 512 + 256 + cc] = lq[0][cc] + lq[1][cc] + lq[2][cc] + lq[3][cc];
        }
    }
}

// stage 2: one 512-thread block; t<256 sums s-partials, t>=256 sums q-partials.
__global__ __launch_bounds__(512) void gme_bns2(const float* __restrict__ PART,
                                                float* __restrict__ ST) {
    int t = threadIdx.x;
    int c = (t < 256) ? t : (t - 256 + 256);  // s at col t, q at col 256+(t-256)
    float acc = 0.f;
#pragma unroll 8
    for (int r = 0; r < 512; ++r) acc += PART[r * 512 + c];
    ST[c] = acc;  // ST[0..255]=sum, ST[256..511]=sumsq
}

// ---------------- GEMM with fused BN1+LeakyReLU on the A operand ----------------
__global__ __launch_bounds__(256) void gme_gemm(const float* __restrict__ P,
                                                const float* __restrict__ ST,
                                                const float* __restrict__ bw,
                                                const float* __restrict__ bb,
                                                const bf16_t* __restrict__ W2B,
                                                bf16_t* __restrict__ QB) {
    __shared__ float s_sc[256], s_sh[256];
    {
        int c = threadIdx.x;
        float mean = ST[c] * (1.f / NN);
        float var = ST[256 + c] * (1.f / NN) - mean * mean;
        float sc = bw[c] * rsqrtf(var + 1e-5f);
        s_sc[c] = sc;
        s_sh[c] = bb[c] - mean * sc;
    }
    __syncthreads();
    int lane = threadIdx.x & 63;
    int wave = blockIdx.x * 4 + (threadIdx.x >> 6);
    if (wave >= NN / 16) return;
    int m0 = wave * 16;
    int r = lane & 15, q = lane >> 4;
    const float* arow = P + (m0 + r) * 256 + q * 8;
    bf16x8 a[8];
#pragma unroll
    for (int kt = 0; kt < 8; ++kt) {
        int k0 = kt * 32 + q * 8;
        float4 u0 = *(const float4*)(arow + kt * 32);
        float4 u1 = *(const float4*)(arow + kt * 32 + 4);
        bf16x8 f;
        f[0] = (bf16_t)lrelu(fmaf(u0.x, s_sc[k0 + 0], s_sh[k0 + 0]));
        f[1] = (bf16_t)lrelu(fmaf(u0.y, s_sc[k0 + 1], s_sh[k0 + 1]));
        f[2] = (bf16_t)lrelu(fmaf(u0.z, s_sc[k0 + 2], s_sh[k0 + 2]));
        f[3] = (bf16_t)lrelu(fmaf(u0.w, s_sc[k0 + 3], s_sh[k0 + 3]));
        f[4] = (bf16_t)lrelu(fmaf(u1.x, s_sc[k0 + 4], s_sh[k0 + 4]));
        f[5] = (bf16_t)lrelu(fmaf(u1.y, s_sc[k0 + 5], s_sh[k0 + 5]));
        f[6] = (bf16_t)lrelu(fmaf(u1.z, s_sc[k0 + 6], s_sh[k0 + 6]));
        f[7] = (bf16_t)lrelu(fmaf(u1.w, s_sc[k0 + 7], s_sh[k0 + 7]));
        a[kt] = f;
    }
#pragma unroll
    for (int nt = 0; nt < 16; ++nt) {
        f32x4 acc = {0.f, 0.f, 0.f, 0.f};
        const bf16_t* brow = W2B + (nt * 16 + r) * 256 + q * 8;
#pragma unroll
        for (int kt = 0; kt < 8; ++kt) {
            bf16x8 bfrag = *(const bf16x8*)(brow + kt * 32);
            acc = __builtin_amdgcn_mfma_f32_16x16x32_bf16(a[kt], bfrag, acc, 0, 0, 0);
        }
        bf16_t* yo = QB + (m0 + q * 4) * 256 + nt * 16 + r;
        yo[0] = (bf16_t)acc[0]; yo[256] = (bf16_t)acc[1];
        yo[512] = (bf16_t)acc[2]; yo[768] = (bf16_t)acc[3];
    }
}

// ---------------- gate only (BN2 applied on the fly, P left raw) ----------------
__global__ __launch_bounds__(256) void gme_x2g(const float* __restrict__ P,
                                               const float* __restrict__ ST,
                                               const float* __restrict__ bw,
                                               const float* __restrict__ bb,
                                               const float* __restrict__ gw,
                                               const float* __restrict__ gb,
                                               float* __restrict__ GATE) {
    int lane = threadIdx.x & 63;
    int node = blockIdx.x * 4 + (threadIdx.x >> 6);
    if (node >= NN) return;
    float4 s = ((const float4*)ST)[lane];
    float4 qq = ((const float4*)(ST + 256))[lane];
    float4 w = ((const float4*)bw)[lane];
    float4 b = ((const float4*)bb)[lane];
    float4 g = ((const float4*)gw)[lane];
    float m0 = s.x * (1.f / NN), m1 = s.y * (1.f / NN), m2 = s.z * (1.f / NN), m3 = s.w * (1.f / NN);
    float sc0 = w.x * rsqrtf(qq.x * (1.f / NN) - m0 * m0 + 1e-5f);
    float sc1 = w.y * rsqrtf(qq.y * (1.f / NN) - m1 * m1 + 1e-5f);
    float sc2 = w.z * rsqrtf(qq.z * (1.f / NN) - m2 * m2 + 1e-5f);
    float sc3 = w.w * rsqrtf(qq.w * (1.f / NN) - m3 * m3 + 1e-5f);
    float sh0 = b.x - m0 * sc0, sh1 = b.y - m1 * sc1, sh2 = b.z - m2 * sc2, sh3 = b.w - m3 * sc3;
    float4 p = ((const float4*)P)[node * 64 + lane];
    float v0 = lrelu(fmaf(p.x, sc0, sh0));
    float v1 = lrelu(fmaf(p.y, sc1, sh1));
    float v2 = lrelu(fmaf(p.z, sc2, sh2));
    float v3 = lrelu(fmaf(p.w, sc3, sh3));
    float dot = v0 * g.x + v1 * g.y + v2 * g.z + v3 * g.w;
#pragma unroll
    for (int off = 32; off > 0; off >>= 1) dot += __shfl_xor(dot, off, 64);
    if (lane == 0) GATE[node] = dot + gb[0];
}

// ---------------- graph segment boundaries ----------------
__global__ void gme_gstart(const int* __restrict__ batch, int* __restrict__ GS) {
    int n = blockIdx.x * 256 + threadIdx.x;
    if (n >= NN) return;
    int b = batch[n];
    if (n == 0) {
        for (int g = 0; g <= b; ++g) GS[g] = 0;
    } else {
        int a = batch[n - 1];
        for (int g = a + 1; g <= b; ++g) GS[g] = n;
    }
    if (n == NN - 1) {
        for (int g = b + 1; g <= NG; ++g) GS[g] = NN;
    }
}

// ---------------- attentional aggregation, BN2+lrelu inline (f32 output) ------
__global__ void gme_attn(const int* __restrict__ GS, const float* __restrict__ GATE,
                         const float* __restrict__ P, const float* __restrict__ ST,
                         const float* __restrict__ bw, const float* __restrict__ bb,
                         float* __restrict__ out) {
    __shared__ float red[256];
    int g = blockIdx.x, t = threadIdx.x;
    int lo = GS[g], hi = GS[g + 1];
    if (lo >= hi) { out[g * 256 + t] = 0.f; return; }
    float mean = ST[t] * (1.f / NN);
    float var = ST[256 + t] * (1.f / NN) - mean * mean;
    float sc = bw[t] * rsqrtf(var + 1e-5f);
    float sh = bb[t] - mean * sc;
    float lm = -3.0e38f;
    for (int n = lo + t; n < hi; n += 256) lm = fmaxf(lm, GATE[n]);
    red[t] = lm; __syncthreads();
    for (int s = 128; s > 0; s >>= 1) { if (t < s) red[t] = fmaxf(red[t], red[t + s]); __syncthreads(); }
    float m = red[0]; __syncthreads();
    float ls = 0.f;
    for (int n = lo + t; n < hi; n += 256) ls += expf(GATE[n] - m);
    red[t] = ls; __syncthreads();
    for (int s = 128; s > 0; s >>= 1) { if (t < s) red[t] += red[t + s]; __syncthreads(); }
    float sinv = 1.f / red[0];
    float acc = 0.f;
    int n = lo;
    for (; n + 2 <= hi; n += 2) {
        float w0 = expf(GATE[n] - m), w1 = expf(GATE[n + 1] - m);
        float p0 = P[n * 256 + t], p1 = P[(n + 1) * 256 + t];
        acc = fmaf(w0, lrelu(fmaf(p0, sc, sh)), acc);
        acc = fmaf(w1, lrelu(fmaf(p1, sc, sh)), acc);
    }
    if (n < hi) {
        float w0 = expf(GATE[n] - m);
        acc = fmaf(w0, lrelu(fmaf(P[n * 256 + t], sc, sh)), acc);
    }
    out[g * 256 + t] = acc * sinv;
}

extern "C" void kernel_launch(void* const* d_in, const int* in_sizes, int n_in,
                              void* d_out, int out_size, void* d_ws, size_t ws_size,
                              hipStream_t stream) {
    const int* node_ids = (const int*)d_in[0];
    const int* edge_index = (const int*)d_in[1];
    const float4* edge_attr = (const float4*)d_in[2];
    const int* batch = (const int*)d_in[3];
    const float* emb = (const float*)d_in[4];
    const float* c1l2w = (const float*)d_in[5];
    const float* c1l2b = (const float*)d_in[6];
    const float* c1lw = (const float*)d_in[7];
    const float* c1lb = (const float*)d_in[8];
    const float* bn1w = (const float*)d_in[9];
    const float* bn1b = (const float*)d_in[10];
    const float* c2l2w = (const float*)d_in[11];
    const float* c2l2b = (const float*)d_in[12];
    const float* c2lw = (const float*)d_in[13];
    const float* c2lb = (const float*)d_in[14];
    const float* bn2w = (const float*)d_in[15];
    const float* bn2b = (const float*)d_in[16];
    const float* gate_w = (const float*)d_in[17];
    const float* gate_b = (const float*)d_in[18];

    char* ws = (char*)d_ws;
    size_t oP = 0;                        // f32 [50000,256]
    size_t oQB = oP + 51200000;           // bf16 [50000,256]
    size_t oS0 = oQB + 25600000;          // int [800000] src
    size_t oS1 = oS0 + 3200000;           // int [800000] node_ids[src]
    size_t oSattr = oS1 + 3200000;        // float4 [800000]
    size_t oRS = oSattr + 12800000;       // int [50001]
    size_t oCNT = oRS + 200064;           // int [50000]
    size_t oCUR = oCNT + 200000;          // int [50000]
    size_t oLP = oCUR + 200000;           // int [50000]
    size_t oBS = oLP + 200000;            // int [256]
    size_t oBX = oBS + 1024;              // int [256]
    size_t oTY = oBX + 1024;              // f32 [51,256]
    size_t oWC1 = oTY + 52224;            // f32 [256,4]
    size_t oCB1 = oWC1 + 4096;            // f32 [256]
    size_t oWC2 = oCB1 + 1024;            // f32 [256,4]
    size_t oCB2 = oWC2 + 4096;            // f32 [256]
    size_t oW2B = oCB2 + 1024;            // bf16 [256,256]
    size_t oST = oW2B + 131072;           // f32 [1024]: ST1+ST2
    size_t oGATE = oST + 4096;            // f32 [50000]
    size_t oGS = oGATE + 200000;          // int [513] -> 2056 pad 2festival064
    size_t oPART = oGS + 2064;            // f32 [512*512] partials (1 MB)

    float* P = (float*)(ws + oP);
    bf16_t* QB = (bf16_t*)(ws + oQB);
    int* S0 = (int*)(ws + oS0);
    int* S1 = (int*)(ws + oS1);
    float4* Sattr = (float4*)(ws + oSattr);
    int* RS = (int*)(ws + oRS);
    int* CNT = (int*)(ws + oCNT);
    int* CUR = (int*)(ws + oCUR);
    int* LP = (int*)(ws + oLP);
    int* BS = (int*)(ws + oBS);
    int* BX = (int*)(ws + oBX);
    float* TY = (float*)(ws + oTY);
    float* WC1 = (float*)(ws + oWC1);
    float* CB1 = (float*)(ws + oCB1);
    float* WC2 = (float*)(ws + oWC2);
    float* CB2 = (float*)(ws + oCB2);
    bf16_t* W2B = (bf16_t*)(ws + oW2B);
    float* ST1 = (float*)(ws + oST);
    float* ST2 = ST1 + 512;
    float* GATE = (float*)(ws + oGATE);
    int* GS = (int*)(ws + oGS);
    float* PART = (float*)(ws + oPART);

    hipMemsetAsync(CNT, 0, NN * sizeof(int), stream);

    gme_setup<<<117, 256, 0, stream>>>(emb, c1lw, c1l2w, c1l2b, c1lb,
                                       c2lw, c2l2w, c2l2b, c2lb,
                                       TY, WC1, CB1, WC2, CB2, W2B);
    gme_count<<<NE / 256, 256, 0, stream>>>(edge_index, CNT);
    gme_scan1<<<256, 256, 0, stream>>>(CNT, LP, BS);
    gme_scan2<<<1, 256, 0, stream>>>(BS, BX, RS);
    gme_scan3<<<256, 256, 0, stream>>>(LP, BX, RS, CUR);
    gme_scatter<<<NE / 256, 256, 0, stream>>>(edge_index, edge_attr, node_ids,
                                              CUR, S0, S1, Sattr);
    gme_gstart<<<(NN + 255) / 256, 256, 0, stream>>>(batch, GS);
    // conv1: rows from 51x256 f32 table via pre-mapped S1
    gme_conv<0><<<NN / 4, 256, 0, stream>>>(RS, S1, Sattr, TY, nullptr, WC1, CB1, P);
    gme_bns1<<<512, 256, 0, stream>>>(P, PART);
    gme_bns2<<<1, 512, 0, stream>>>(PART, ST1);
    gme_gemm<<<(NN / 16 + 3) / 4, 256, 0, stream>>>(P, ST1, bn1w, bn1b, W2B, QB);
    // conv2: rows from bf16 y2 table via S0
    gme_conv<1><<<NN / 4, 256, 0, stream>>>(RS, S0, Sattr, nullptr, QB, WC2, CB2, P);
    gme_bns1<<<512, 256, 0, stream>>>(P, PART);
    gme_bns2<<<1, 512, 0, stream>>>(PART, ST2);
    gme_x2g<<<NN / 4, 256, 0, stream>>>(P, ST2, bn2w, bn2b, gate_w, gate_b, GATE);
    gme_attn<<<NG, 256, 0, stream>>>(GS, GATE, P, ST2, bn2w, bn2b, (float*)d_out);
}